// Round 1
// baseline (230.400 us; speedup 1.0000x reference)
//
#include <hip/hip_runtime.h>

#define NFFT 1024
#define TPB 256  // 4 waves per block, one 1024-pt row per wave

// ---------- complex helpers (same convention as verified 224us kernel) ----------
__device__ __forceinline__ float2 cmul(float2 a, float2 b) {
  return make_float2(fmaf(a.x, b.x, -a.y * b.y), fmaf(a.x, b.y, a.y * b.x));
}
__device__ __forceinline__ float2 cadd(float2 a, float2 b) { return make_float2(a.x + b.x, a.y + b.y); }
__device__ __forceinline__ float2 csub(float2 a, float2 b) { return make_float2(a.x - b.x, a.y - b.y); }

// y_k = sum_r v_r * e^{-2*pi*i*k*r/4}
__device__ __forceinline__ void dft4(const float2 v[4], float2 y[4]) {
  float2 s02 = cadd(v[0], v[2]), d02 = csub(v[0], v[2]);
  float2 s13 = cadd(v[1], v[3]), d13 = csub(v[1], v[3]);
  y[0] = cadd(s02, s13);
  y[2] = csub(s02, s13);
  y[1] = make_float2(d02.x + d13.y, d02.y - d13.x);  // d02 + (-i)*d13
  y[3] = make_float2(d02.x - d13.y, d02.y + d13.x);  // d02 + (+i)*d13
}

// ---------- DPP quad shuffles: lane ^ 2 and lane ^ 1 within each quad ----------
__device__ __forceinline__ float dpp_xor2(float x) {
  // quad_perm [2,3,0,1] = 2 | 3<<2 | 0<<4 | 1<<6 = 0x4E
  return __int_as_float(__builtin_amdgcn_update_dpp(0, __float_as_int(x), 0x4E, 0xF, 0xF, true));
}
__device__ __forceinline__ float dpp_xor1(float x) {
  // quad_perm [1,0,3,2] = 1 | 0<<2 | 3<<4 | 2<<6 = 0xB1
  return __int_as_float(__builtin_amdgcn_update_dpp(0, __float_as_int(x), 0xB1, 0xF, 0xF, true));
}

// ---------- in-lane 16-point FFT over the 16 registers ----------
// Input: z[c] = time samples (c = 0..15 at stride of caller's choosing).
// Output: slot s holds Z[KOF(s)] with KOF(s) = (s>>2) | ((s&3)<<2)  (base-4 digit reverse).
// All twiddles W16^k are compile-time constants (no sincos).
__device__ __forceinline__ void fft16(float2 z[16]) {
  float2 g[16];
  #pragma unroll
  for (int c0 = 0; c0 < 4; ++c0) {
    float2 v[4] = {z[c0], z[c0 + 4], z[c0 + 8], z[c0 + 12]};
    float2 y[4];
    dft4(v, y);
    g[4 * c0 + 0] = y[0]; g[4 * c0 + 1] = y[1]; g[4 * c0 + 2] = y[2]; g[4 * c0 + 3] = y[3];
  }
  // g[4*c0 + k0] *= W16^{c0*k0};  W16^k = (cos(2pi k/16), -sin(2pi k/16))
  const float C1 = 0.92387953251128674f, S1 = 0.38268343236508978f, R = 0.70710678118654752f;
  g[5]  = cmul(g[5],  make_float2( C1, -S1));   // (1,1) W^1
  g[6]  = cmul(g[6],  make_float2(  R,  -R));   // (1,2) W^2
  g[7]  = cmul(g[7],  make_float2( S1, -C1));   // (1,3) W^3
  g[9]  = cmul(g[9],  make_float2(  R,  -R));   // (2,1) W^2
  g[10] = make_float2(g[10].y, -g[10].x);       // (2,2) W^4 = -i
  g[11] = cmul(g[11], make_float2( -R,  -R));   // (2,3) W^6
  g[13] = cmul(g[13], make_float2( S1, -C1));   // (3,1) W^3
  g[14] = cmul(g[14], make_float2( -R,  -R));   // (3,2) W^6
  g[15] = cmul(g[15], make_float2(-C1,  S1));   // (3,3) W^9
  #pragma unroll
  for (int k0 = 0; k0 < 4; ++k0) {
    float2 v[4] = {g[k0], g[4 + k0], g[8 + k0], g[12 + k0]};
    float2 y[4];
    dft4(v, y);
    z[4 * k0 + 0] = y[0]; z[4 * k0 + 1] = y[1]; z[4 * k0 + 2] = y[2]; z[4 * k0 + 3] = y[3];
  }
}

// Multiply slot-ordered spectrum by u^kappa (kappa = KOF(slot)), via running powers.
__device__ __forceinline__ void twiddle_apply(float2 z[16], float2 u) {
  float2 w = u;
  #pragma unroll
  for (int k = 1; k < 16; ++k) {
    const int s = ((k & 3) << 2) | (k >> 2);  // slot with KOF(slot) == k
    z[s] = cmul(z[s], w);
    w = cmul(w, u);
  }
}

// One wave computes one 1024-pt FFT:
//   n = (4m+p) + 64c   (lane n' = 4m+p, reg c)
//   X[kap + 16t + 256u] = sum_p W4^{up} W64^{pt} sum_m W16^{mt}
//                         [ W1024^{n' kap} sum_c W16^{c kap} x[n' + 64c] ]
// Phase1: in-lane fft16 over c + twiddle W1024^{lane*kap}.
// Transpose (intra-wave LDS, XOR-swizzled, no s_barrier): lane2 = p + 4*kap gets reg m.
// Phase2: in-lane fft16 over m + twiddle W64^{p*t}.
// Final: radix-4 across quad lanes (p) via DPP; store X[kap + 16t + 256*ur(p)].
__global__ __launch_bounds__(TPB, 4) void fft1024_kernel(const float* __restrict__ in,
                                                         float* __restrict__ out,
                                                         int nrows) {
  __shared__ float2 lds[TPB / 64][NFFT];  // 8 KB per wave, wave-private
  const int wv = threadIdx.x >> 6;
  const int lane = threadIdx.x & 63;
  const int row = blockIdx.x * (TPB / 64) + wv;
  if (row >= nrows) return;

  const float2* __restrict__ xin = reinterpret_cast<const float2*>(in) + (size_t)row * NFFT;
  float2* __restrict__ xout = reinterpret_cast<float2*>(out) + (size_t)row * NFFT;

  float2 z[16];
  // ---- load: z[c] = x[lane + 64c]  (each instr: 64 lanes x 8B = 512B contiguous)
  #pragma unroll
  for (int c = 0; c < 16; ++c) z[c] = xin[lane + 64 * c];

  // ---- phase 1: 16-pt FFT over regs; slot s holds F1[KOF(s)]
  fft16(z);

  // twiddle W1024^{lane * kap}
  float sn, cs;
  __sincosf((float)lane * (-6.2831853071795864769f / 1024.0f), &sn, &cs);
  twiddle_apply(z, make_float2(cs, sn));

  // ---- transpose via wave-private LDS (no barrier; intra-wave waitcnt only)
  // writer: lane n' (m = n'>>2, p = n'&3), slot kap -> addr m*64 + ((p+4kap) ^ m)
  // reader: lane l2 = p + 4kap, reg m        -> addr m*64 + (l2 ^ m)
  // both sides: 4 lanes per bank-pair = 2 lanes/bank -> conflict-free
  {
    float2* buf = lds[wv];
    const int m = lane >> 2, p = lane & 3;
    #pragma unroll
    for (int s = 0; s < 16; ++s) {
      const int kap = (s >> 2) | ((s & 3) << 2);
      buf[m * 64 + ((p + 4 * kap) ^ m)] = z[s];
    }
    asm volatile("s_waitcnt lgkmcnt(0)" ::: "memory");
    __builtin_amdgcn_sched_barrier(0);
    #pragma unroll
    for (int mm = 0; mm < 16; ++mm) z[mm] = buf[mm * 64 + (lane ^ mm)];
  }

  // ---- phase 2: 16-pt FFT over m; slot s holds I[KOF(s)] for (kap = lane>>2, p = lane&3)
  fft16(z);

  // twiddle W64^{p * t}
  const int p = lane & 3;
  __sincosf((float)p * (-6.2831853071795864769f / 64.0f), &sn, &cs);
  twiddle_apply(z, make_float2(cs, sn));

  // ---- final radix-4 across quad lanes (digit p) via DPP, fully in registers
  // stage1 (xor 2): lanes {0,1}: a_p = self+partner ; lanes {2,3}: b = partner-self
  // lane 3 then multiplies by W4^1 = -i ; stage2 (xor 1): +/- by lane bit0.
  // Result: lane with sub-index p holds output digit u = bitrev2(p).
  const float sgn1 = (lane & 2) ? -1.0f : 1.0f;
  const float sgn2 = (lane & 1) ? -1.0f : 1.0f;
  const bool tw3 = ((lane & 3) == 3);
  #pragma unroll
  for (int s = 0; s < 16; ++s) {
    float px = dpp_xor2(z[s].x), py = dpp_xor2(z[s].y);
    float ax = fmaf(sgn1, z[s].x, px), ay = fmaf(sgn1, z[s].y, py);
    float bx = tw3 ? ay : ax;
    float by = tw3 ? -ax : ay;
    float qx = dpp_xor1(bx), qy = dpp_xor1(by);
    z[s].x = fmaf(sgn2, bx, qx);
    z[s].y = fmaf(sgn2, by, qy);
  }

  // ---- store: X[kap + 16*t + 256*ur(p)], t = KOF(s)
  const int kap = lane >> 2;
  const int ur = ((p & 1) << 1) | (p >> 1);  // bitrev2(p)
  float2* __restrict__ orow = xout + kap + 256 * ur;
  #pragma unroll
  for (int s = 0; s < 16; ++s) {
    const int t = (s >> 2) | ((s & 3) << 2);
    orow[16 * t] = z[s];  // per instr: 4 aligned 128B segments -> fully-used cache lines
  }
}

extern "C" void kernel_launch(void* const* d_in, const int* in_sizes, int n_in,
                              void* d_out, int out_size, void* d_ws, size_t ws_size,
                              hipStream_t stream) {
  const float* x = (const float*)d_in[0];
  float* out = (float*)d_out;
  const int rows = in_sizes[0] / (2 * NFFT);  // 16384 rows of 1024 complex
  const int rpb = TPB / 64;                   // 4 rows per block (1 per wave)
  const int blocks = (rows + rpb - 1) / rpb;
  fft1024_kernel<<<blocks, TPB, 0, stream>>>(x, out, rows);
}